// Round 1
// baseline (1038.586 us; speedup 1.0000x reference)
//
#include <hip/hip_runtime.h>

// Problem constants (fixed by the reference):
//   N=10000, L=5, A=6, C=20, C2=20
//   pairs = L*A = 30; stats per n = 600 floats; elems per n = 12000 (= 3000 float4)
// Output layout (flat concat): p_Q [200000] | posterior [120M] | rightmost [120M]

#define NN        10000
#define POST_OFF  200000
#define RT_OFF    (200000 + 120000000)
#define TOTAL4    30000000            // N * 3000 float4 per output stream

// ---------------------------------------------------------------------------
// Kernel A: per-n reduction work only (no bulk streaming).
//   - invb[n*30+p] = 1/neighbDim  -> ws[0 .. N*30)
//   - wgt[p] = layerS*arcS        -> ws[N*30 .. N*30+30)   (written by block 0)
//   - p_Q[n,c]                    -> out[0 .. 200000)
// ---------------------------------------------------------------------------
__global__ __launch_bounds__(256) void cgmm_prep(
    const float* __restrict__ stats,   // [N,5,6,20]
    const float* __restrict__ layerS,  // [5]
    const float* __restrict__ arcS,    // [5,6]
    const float* __restrict__ T,       // [5,6,20,20]
    float* __restrict__ out,
    float* __restrict__ ws)
{
    __shared__ __attribute__((aligned(16))) float s[600];
    __shared__ float invb[30];
    __shared__ float wgt[30];
    __shared__ float red[200];

    const int n = blockIdx.x;
    const int t = threadIdx.x;

    const float* sn = stats + (size_t)n * 600;
    for (int i = t; i < 600; i += 256) s[i] = sn[i];
    __syncthreads();

    if (t < 30) {
        float sum = 0.f;
        #pragma unroll
        for (int j = 0; j < 20; ++j) sum += s[t * 20 + j];
        const float iv = (sum == 0.f) ? 1.f : 1.f / sum;
        invb[t] = iv;
        ws[(size_t)n * 30 + t] = iv;
        const float w = layerS[t / 6] * arcS[t];
        wgt[t] = w;
        if (n == 0) ws[(size_t)NN * 30 + t] = w;  // n-independent table, write once
    }
    __syncthreads();

    const float4* T4 = (const float4*)T;   // 3000 float4, L2-resident
    const float4* s4 = (const float4*)s;

    // Same (slot,r) decomposition as the streaming kernel, but only the dot
    // products needed for p_Q; no global stores -> no vmcnt drain pressure.
    float acc = 0.f;
    if (t < 200) {
        const int r = t % 100;
        const int q = r % 5;
        #pragma unroll
        for (int pb = 0; pb < 30; pb += 2) {
            const int p = pb + t / 100;
            const float4 tv = T4[p * 100 + r];
            const float4 sv = s4[p * 5 + q];
            acc += (tv.x * sv.x + tv.y * sv.y + tv.z * sv.z + tv.w * sv.w)
                   * (invb[p] * wgt[p]);
        }
        red[t] = acc;
    }
    __syncthreads();

    if (t < 20) {
        float pq = 0.f;
        #pragma unroll
        for (int k = 0; k < 5; ++k)
            pq += red[t * 5 + k] + red[100 + t * 5 + k];
        out[(size_t)n * 20 + t] = pq;
    }
}

// ---------------------------------------------------------------------------
// Kernel B: pure streaming. One float4 of rightmost+posterior per iteration.
// No LDS, no barriers, no partial waves; consecutive lanes -> consecutive
// 16 B addresses in both output streams. invb/wgt come from the workspace.
// ---------------------------------------------------------------------------
__global__ __launch_bounds__(256) void cgmm_stream(
    const float* __restrict__ stats,
    const float* __restrict__ T,
    const float* __restrict__ ws,
    float* __restrict__ out)
{
    const float4* T4 = (const float4*)T;
    const float4* S4 = (const float4*)stats;
    const float* invb = ws;
    const float* wgt  = ws + (size_t)NN * 30;
    float4* post4 = (float4*)(out + POST_OFF);
    float4* rt4   = (float4*)(out + RT_OFF);

    int idx = blockIdx.x * 256 + threadIdx.x;
    const int stride = gridDim.x * 256;
    for (; idx < TOTAL4; idx += stride) {
        const int n   = idx / 3000;          // magic-mul division (const)
        const int rem = idx - n * 3000;      // = p*100 + c*5 + q
        const int p   = rem / 100;
        const int r   = rem - p * 100;
        const int q   = r % 5;

        const float4 tv = T4[rem];                       // L2-resident (48 KB)
        const float4 sv = S4[(size_t)n * 150 + p * 5 + q]; // wave-broadcast, L1
        const float iw  = invb[n * 30 + p];              // uniform per 100 idx
        const float w   = wgt[p];                        // uniform per 100 idx

        float4 rt;
        rt.x = tv.x * sv.x * iw;
        rt.y = tv.y * sv.y * iw;
        rt.z = tv.z * sv.z * iw;
        rt.w = tv.w * sv.w * iw;
        float4 po;
        po.x = rt.x * w; po.y = rt.y * w;
        po.z = rt.z * w; po.w = rt.w * w;

        rt4[idx]   = rt;   // contiguous 16 B/lane, full-line stores
        post4[idx] = po;
    }
}

// ---------------------------------------------------------------------------
// Fallback: previous single-kernel version (used only if ws is too small).
// ---------------------------------------------------------------------------
__global__ __launch_bounds__(256) void cgmm_kernel(
    const float* __restrict__ stats,
    const float* __restrict__ layerS,
    const float* __restrict__ arcS,
    const float* __restrict__ T,
    float* __restrict__ out)
{
    __shared__ __attribute__((aligned(16))) float s[600];
    __shared__ float invb[30];
    __shared__ float wgt[30];
    __shared__ float red[200];

    const int n = blockIdx.x;
    const int t = threadIdx.x;

    const float* sn = stats + (size_t)n * 600;
    for (int i = t; i < 600; i += 256) s[i] = sn[i];
    __syncthreads();

    if (t < 30) {
        float sum = 0.f;
        #pragma unroll
        for (int j = 0; j < 20; ++j) sum += s[t * 20 + j];
        invb[t] = (sum == 0.f) ? 1.f : 1.f / sum;
        wgt[t]  = layerS[t / 6] * arcS[t];
    }
    __syncthreads();

    const float4* T4 = (const float4*)T;
    const float4* s4 = (const float4*)s;
    float4* post4 = (float4*)(out + POST_OFF) + (size_t)n * 3000;
    float4* rt4o  = (float4*)(out + RT_OFF)   + (size_t)n * 3000;

    float acc = 0.f;
    if (t < 200) {
        const int r = t % 100;
        const int q = r % 5;
        #pragma unroll
        for (int pb = 0; pb < 30; pb += 2) {
            const int p = pb + t / 100;
            const float inv = invb[p];
            const float w   = wgt[p];
            const float4 tv = T4[p * 100 + r];
            const float4 sv = s4[p * 5 + q];
            float4 rt;
            rt.x = tv.x * sv.x * inv;
            rt.y = tv.y * sv.y * inv;
            rt.z = tv.z * sv.z * inv;
            rt.w = tv.w * sv.w * inv;
            float4 po;
            po.x = rt.x * w; po.y = rt.y * w;
            po.z = rt.z * w; po.w = rt.w * w;
            rt4o [p * 100 + r] = rt;
            post4[p * 100 + r] = po;
            acc += po.x + po.y + po.z + po.w;
        }
        red[t] = acc;
    }
    __syncthreads();

    if (t < 20) {
        float pq = 0.f;
        #pragma unroll
        for (int k = 0; k < 5; ++k)
            pq += red[t * 5 + k] + red[100 + t * 5 + k];
        out[(size_t)n * 20 + t] = pq;
    }
}

extern "C" void kernel_launch(void* const* d_in, const int* in_sizes, int n_in,
                              void* d_out, int out_size, void* d_ws, size_t ws_size,
                              hipStream_t stream) {
    const float* stats  = (const float*)d_in[0];
    const float* layerS = (const float*)d_in[1];
    const float* arcS   = (const float*)d_in[2];
    const float* T      = (const float*)d_in[3];
    float* out = (float*)d_out;

    const size_t ws_need = (size_t)(NN * 30 + 30) * sizeof(float);  // ~1.2 MB
    if (d_ws != nullptr && ws_size >= ws_need) {
        float* ws = (float*)d_ws;
        cgmm_prep  <<<dim3(NN),   dim3(256), 0, stream>>>(stats, layerS, arcS, T, out, ws);
        cgmm_stream<<<dim3(2048), dim3(256), 0, stream>>>(stats, T, ws, out);
    } else {
        cgmm_kernel<<<dim3(NN), dim3(256), 0, stream>>>(stats, layerS, arcS, T, out);
    }
}